// Round 1
// 3592.458 us; speedup vs baseline: 3.8077x; 3.8077x over previous
//
#include <hip/hip_runtime.h>

#define XD    64      // x_dim
#define HID   256     // hidden
#define G4    1024    // 4*hidden
#define TLEN  2048
#define BATCH 64
#define NPART 8       // blocks per chain
#define UPB   32      // hidden units per part
#define CPB   128     // gate columns per part (4 gates x 32 units)
#define TSTRIDE 16    // ints between chains' handshake-token groups (64B line)

typedef unsigned int uint;

__device__ __forceinline__ float sigmf(float x) {
    return 1.0f / (1.0f + __expf(-x));
}
// tanh(x) = 1 - 2/(exp(2x)+1); __expf saturation gives correct +/-1 tails
__device__ __forceinline__ float tanhfast(float x) {
    return 1.0f - 2.0f / (1.0f + __expf(2.0f * x));
}

// ---- fused (h, stamp) 8-byte pair transport ----------------------------
// fast path (parts verified same-XCD): sc0 = bypass CU L1, coherent at the
// shared per-XCD L2 (~200cy). nt on the poll load: never allocate in L1, so
// repeated polls can't be served stale out of L1.
__device__ __forceinline__ uint2 ld_pair_sc0(const uint2* p) {
    uint2 r;
    asm volatile("global_load_dwordx2 %0, %1, off sc0 nt\n\ts_waitcnt vmcnt(0)"
                 : "=v"(r) : "v"(p) : "memory");
    return r;
}
__device__ __forceinline__ void st_pair_sc0(uint2* p, uint2 v) {
    asm volatile("global_store_dwordx2 %0, %1, off sc0" :: "v"(p), "v"(v) : "memory");
}
// slow path (parts on different XCDs): device-scope 8B atomics via LLC —
// same semantics the previous (verified-passing) flag protocol relied on.
__device__ __forceinline__ uint2 ld_pair_dev(const uint2* p) {
    unsigned long long u = __hip_atomic_load((const unsigned long long*)p,
                                             __ATOMIC_RELAXED, __HIP_MEMORY_SCOPE_AGENT);
    uint2 r; r.x = (uint)(u & 0xffffffffu); r.y = (uint)(u >> 32); return r;
}
__device__ __forceinline__ void st_pair_dev(uint2* p, uint2 v) {
    unsigned long long u = ((unsigned long long)v.y << 32) | (unsigned long long)v.x;
    __hip_atomic_store((unsigned long long*)p, u, __ATOMIC_RELAXED, __HIP_MEMORY_SCOPE_AGENT);
}

// Zero pair stamps (both buffers) + handshake tokens. ws is re-poisoned to
// 0xAA before every timed call; poison never FALSELY matches (stamp compare is
// exact equality, token compare is >=256 signed with poison negative), but we
// zero anyway so correctness never depends on the poisoning contract.
__global__ void init_ws(unsigned long long* __restrict__ pairs, int* __restrict__ tok) {
    const int i = blockIdx.x * 256 + threadIdx.x;       // 64 blocks x 256 thr
    pairs[i] = 0ULL;                                    // buffer 0
    pairs[BATCH * HID + i] = 0ULL;                      // buffer 1
    if (threadIdx.x < TSTRIDE) tok[blockIdx.x * TSTRIDE + threadIdx.x] = 0;
}

// 512 blocks = 64 chains x 8 parts, 256 threads, 2 blocks/CU (all co-resident).
// Block decode is CHAIN-MAJOR: chain = blk%64, part = blk/64, so all 8 parts of
// a chain share blk%8 -> the same XCD under the measured round-robin dispatch.
// A runtime XCC_ID consensus handshake VERIFIES co-location; if it fails, the
// chain falls back to device-scope pairs (correctness never depends on mapping).
__global__ __launch_bounds__(256, 2)
void lstm_par(const float* __restrict__ x,     // (B, T, 64)
              const float* __restrict__ wih,   // (1024, 64) row-major
              const float* __restrict__ whh,   // (1024, 256) row-major
              const float* __restrict__ bias,  // (1024)
              float* __restrict__ out,         // (B, T, 256)
              uint2* __restrict__ pairs,       // (2, B, 256) {h_bits, stamp}
              int* __restrict__ tok)           // (B, TSTRIDE) handshake tokens
{
    const int b    = blockIdx.x & 63;          // chain
    const int part = blockIdx.x >> 6;          // part: blocks {c, 64+c, ...}
    const int tid  = threadIdx.x;
    const int col  = tid >> 1;
    const int half = tid & 1;
    const int q    = col >> 5;                 // gate index (i,f,g,o)
    const int u    = col & 31;                 // unit within part
    const int j    = q * 256 + part * UPB + u; // global gate column

    __shared__ __align__(16) float vec[XD + HID]; // [x_t | h_{t-1}]
    __shared__ float zsh[CPB];
    __shared__ int fastsh;

    // ---- one-time: weights into registers (amortized over 2048 steps) ----
    float4 w4[40];
    {
        const float4* wihr = (const float4*)(wih + (size_t)j * XD);
        const float4* whhr = (const float4*)(whh + (size_t)j * HID);
        if (half == 0) {
            #pragma unroll
            for (int i = 0; i < 16; ++i) w4[i] = wihr[i];        // w_ih[j][0:64]
            #pragma unroll
            for (int i = 0; i < 24; ++i) w4[16 + i] = whhr[i];   // w_hh[j][0:96]
        } else {
            #pragma unroll
            for (int i = 0; i < 40; ++i) w4[i] = whhr[24 + i];   // w_hh[j][96:256]
        }
    }
    const float bj = (half == 0) ? bias[j] : 0.0f;

    // ---- one-time XCD co-location handshake (device-scope, reliable) ----
    {
        int xcc;
        asm volatile("s_getreg_b32 %0, hwreg(HW_REG_XCC_ID)" : "=s"(xcc));
        xcc &= 15;
        int* tb = tok + b * TSTRIDE;
        if (tid == 0)
            __hip_atomic_store(tb + part, 256 + xcc, __ATOMIC_RELEASE,
                               __HIP_MEMORY_SCOPE_AGENT);
        if (tid < 64) {
            const int lane = tid & 7;          // 64 lanes cover 8 tokens
            int v = 0, guard = 0;
            for (;;) {
                v = __hip_atomic_load(tb + lane, __ATOMIC_RELAXED,
                                      __HIP_MEMORY_SCOPE_AGENT);
                if (__all(v >= 256)) break;
                __builtin_amdgcn_s_sleep(2);
                if (++guard > 200000) break;   // catastrophe-only
            }
            const int ok = __all(v >= 256);
            const int v0 = __shfl(v, 0);
            const int eq = (ok && __all(v == v0)) ? 1 : 0;
            if (tid == 0) fastsh = eq;
        }
        __syncthreads();
    }
    const bool fast = (fastsh != 0);

    uint2* __restrict__ pb0 = pairs + (size_t)b * HID;            // buffer 0
    uint2* __restrict__ pb1 = pairs + (size_t)(BATCH + b) * HID;  // buffer 1
    const float* __restrict__ xb = x + (size_t)b * TLEN * XD;
    float* __restrict__ ob = out + (size_t)b * TLEN * HID;

    float c = 0.0f;                       // thread tid<32 owns cell of unit tid
    float xreg = (tid < XD) ? xb[tid] : 0.0f;   // x_0 prefetch

    for (int t = 0; t < TLEN; ++t) {
        // ---- gather h_{t-1}: each thread polls ITS fused pair. The stamp
        // arrives in the same 8B load as the data: one L2 (fast) / LLC (slow)
        // leg instead of flag-poll + separate h-load.
        if (t > 0) {
            const uint2* src = ((t & 1) ? pb0 : pb1) + tid;  // buf (t-1)&1
            uint2 pr;
            int it = 0;
            for (;;) {
                // escalation insurance: if sc0 polling ever fails to observe
                // the store (unexpected), fall to device-scope loads.
                pr = (fast && it < 1024) ? ld_pair_sc0(src) : ld_pair_dev(src);
                if (pr.y == (uint)t) break;   // exact-match: deadlock (visible
                __builtin_amdgcn_s_sleep(1);  // failure) over silent staleness
                if (++it > 100000) break;     // hang-guard: corrupt, don't hang
            }
            vec[XD + tid] = __uint_as_float(pr.x);
        } else {
            vec[XD + tid] = 0.0f;             // h_{-1} = 0
        }
        if (tid < XD) vec[tid] = xreg;
        __syncthreads(); // (B)

        // prefetch next x (latency overlapped by compute + next poll)
        if (t + 1 < TLEN && tid < XD) xreg = xb[(size_t)(t + 1) * XD + tid];

        // ---- 160-FMA half-dot: register weights x LDS-broadcast operands ----
        float4 acc = make_float4(bj, 0.f, 0.f, 0.f);
        const float4* vb = ((const float4*)vec) + half * 40;
        #pragma unroll
        for (int i = 0; i < 40; ++i) {
            const float4 v = vb[i];
            acc.x = fmaf(w4[i].x, v.x, acc.x);
            acc.y = fmaf(w4[i].y, v.y, acc.y);
            acc.z = fmaf(w4[i].z, v.z, acc.z);
            acc.w = fmaf(w4[i].w, v.w, acc.w);
        }
        float z = (acc.x + acc.y) + (acc.z + acc.w);
        z += __shfl_xor(z, 1);            // combine the two halves of column j
        if (half == 0) zsh[col] = z;
        __syncthreads(); // (C)

        // ---- gates, state update, publish (threads 0..31; all in wave 0) ----
        if (tid < UPB) {
            const float zi = zsh[tid];
            const float zf = zsh[UPB + tid];
            const float zg = zsh[2 * UPB + tid];
            const float zo = zsh[3 * UPB + tid];
            const float ig = sigmf(zi);
            const float fg = sigmf(zf);
            const float gg = tanhfast(zg);
            const float og = sigmf(zo);
            c = fg * c + ig * gg;
            const float h = og * tanhfast(c);
            // fused publish: stamp travels WITH the value; no release drain,
            // no separate flag store. Single 8B store is消 atomic in practice
            // (one instruction, one line) and exactly ordered by data-dep.
            uint2 pv; pv.x = __float_as_uint(h); pv.y = (uint)(t + 1);
            uint2* dst = ((t & 1) ? pb1 : pb0) + part * UPB + tid;
            if (fast) st_pair_sc0(dst, pv);
            else      st_pair_dev(dst, pv);
            // output store AFTER the publish: off the inter-part critical path
            ob[(size_t)t * HID + part * UPB + tid] = h;
        }
    }
}

extern "C" void kernel_launch(void* const* d_in, const int* in_sizes, int n_in,
                              void* d_out, int out_size, void* d_ws, size_t ws_size,
                              hipStream_t stream) {
    const float* x    = (const float*)d_in[0];
    const float* wih  = (const float*)d_in[1];
    const float* whh  = (const float*)d_in[2];
    const float* bias = (const float*)d_in[3];
    float* out = (float*)d_out;

    uint2* pairs = (uint2*)d_ws;  // 2*64*256 pairs = 256 KB
    int*   tok   = (int*)((char*)d_ws + (size_t)2 * BATCH * HID * sizeof(uint2)); // 4 KB

    hipLaunchKernelGGL(init_ws, dim3(BATCH), dim3(256), 0, stream,
                       (unsigned long long*)d_ws, tok);
    hipLaunchKernelGGL(lstm_par, dim3(BATCH * NPART), dim3(256), 0, stream,
                       x, wih, whh, bias, out, pairs, tok);
}